// Round 6
// baseline (2288.834 us; speedup 1.0000x reference)
//
#include <hip/hip_runtime.h>

// y[n,o] = sum_r e[n,r]*(W[r]@x[n])[o] + (e@b)[n,o]
// One bf16 GEMM, K = 8256: k = il*64 + ih*32 + r (i = 128*ih + il), bias tile appended.
// A'[n,k] = e[n,r]*x[n,i] built on the fly (e-row in regs, x prefetched float4/4-tiles).
// B^T = Wb[o][k] bf16 in d_ws; LDS XOR-swizzled (A: swizzled ds_write; B: pre-swizzled
// gld_lds source). 4 phases/K-tile, counted vmcnt(4) (T3+T4), setprio around MFMA (T5),
// tri-buffered B. __launch_bounds__(512) ONLY — round 4's (512,2) forced a 128-VGPR
// fit for a ~215-VGPR body -> acc spilled to scratch (FETCH 2.9GB, WRITE 847MB).

typedef __attribute__((ext_vector_type(4))) float f32x4;
typedef __attribute__((ext_vector_type(8))) short short8;
typedef __attribute__((ext_vector_type(8))) unsigned short ushort8;

#define R_DIM 32
#define I_DIM 256
#define O_DIM 256
#define KW    8192
#define KEXT  8256            // +64: [8192,8224)=b^T, rest 0
#define BM    224
#define BN    256
#define BK    64
#define NT    (KEXT / BK)     // 129
#define NTHR  512

__device__ __forceinline__ unsigned short f2bf(float f) {
  unsigned u = __builtin_bit_cast(unsigned, f);
  u += 0x7FFFu + ((u >> 16) & 1u);  // RNE
  return (unsigned short)(u >> 16);
}

__device__ __forceinline__ unsigned pk2(float a, float b) {
  return (unsigned)f2bf(a) | ((unsigned)f2bf(b) << 16);
}

__device__ __forceinline__ void gld_lds16(const void* g, void* l) {
  __builtin_amdgcn_global_load_lds(
      (const __attribute__((address_space(1))) unsigned int*)g,
      (__attribute__((address_space(3))) unsigned int*)l, 16, 0, 0);
}

// ---- prep: Wb[o][k] = bf16(W[r,o,i]), k = il*64+ih*32+r, i = 128*ih+il ----
__global__ void prep_w(const float* __restrict__ W, const float* __restrict__ b,
                       unsigned short* __restrict__ Wb) {
  const int id = blockIdx.x * 256 + threadIdx.x;   // 256 * 2064 threads exactly
  const int o  = id / (KEXT / 4);
  const int k4 = (id - o * (KEXT / 4)) * 4;
  float v[4];
  if (k4 < KW) {
    const int r  = k4 & 31;
    const int ih = (k4 >> 5) & 1;
    const int il = k4 >> 6;
    const int i  = 128 * ih + il;
#pragma unroll
    for (int j = 0; j < 4; ++j)
      v[j] = W[((size_t)((r + j) * O_DIM + o)) * I_DIM + i];
  } else {
    const int kk = k4 - KW;
#pragma unroll
    for (int j = 0; j < 4; ++j)
      v[j] = (kk + j < R_DIM) ? b[(kk + j) * O_DIM + o] : 0.f;
  }
  uint2 pk;
  pk.x = pk2(v[0], v[1]);
  pk.y = pk2(v[2], v[3]);
  *(uint2*)&Wb[(size_t)o * KEXT + k4] = pk;
}

// ---- main: 512 thr, 8 waves (2M x 4N), wave tile 112x64, 4-phase counted-vmcnt ----
__global__ __launch_bounds__(NTHR) void lkg8q(
    const float* __restrict__ x, const float* __restrict__ e,
    const unsigned short* __restrict__ Wb, float* __restrict__ out, int Ntot) {
  __shared__ unsigned short Al[2][BM * BK];   // 2 x 28 KB
  __shared__ unsigned short Bl[3][BN * BK];   // 3 x 32 KB  (152 KB total)

  const int tid  = threadIdx.x;
  const int lane = tid & 63;
  const int w    = tid >> 6;     // 0..7
  const int wr   = w >> 2;       // 0..1
  const int wc   = w & 3;        // 0..3
  const int l15  = lane & 15;
  const int sx   = (l15 & 7) << 4;
  const int kb0  = (lane >> 4) << 4;

  const int  m0   = (int)blockIdx.x * BM;
  const bool stA  = (tid < 2 * BM);        // waves 0..6 stage A
  const int  srow = tid >> 1;              // 0..223
  const int  half = tid & 1;               // ih of this thread's columns
  const int  gr   = min(m0 + (stA ? srow : 0), Ntot - 1);

  // B gld_lds source-side swizzle (rule #21: linear dest + inverse-swz source)
  const int bro = lane >> 3;              // row within 8-row group
  const int bch = (lane & 7) ^ bro;       // pre-swizzled chunk index

  // e-row cached in registers (fixed row per thread for the whole K loop)
  float er[32];
  if (stA) {
#pragma unroll
    for (int q = 0; q < 8; ++q) {
      const float4 ev = *(const float4*)&e[(size_t)gr * R_DIM + q * 4];
      er[q * 4 + 0] = ev.x; er[q * 4 + 1] = ev.y;
      er[q * 4 + 2] = ev.z; er[q * 4 + 3] = ev.w;
    }
  }
  const float* xrow = x + (size_t)gr * I_DIM + half * 128;

  f32x4 acc[7][4];
#pragma unroll
  for (int a = 0; a < 7; ++a)
#pragma unroll
    for (int c = 0; c < 4; ++c) acc[a][c] = (f32x4){0.f, 0.f, 0.f, 0.f};

  auto issueB2 = [&](unsigned short* Bd, int t2, int gb) {
    const size_t k0 = (size_t)t2 * BK;
#pragma unroll
    for (int g = gb; g < gb + 2; ++g)
      gld_lds16(Wb + (size_t)(w * 32 + g * 8 + bro) * KEXT + k0 + bch * 8,
                Bd + (w * 32 + g * 8) * BK);
  };
  auto stageA2 = [&](unsigned short* Ad, float xs, int hb) {
    if (!stA) return;
    char* rowp = (char*)(Ad + srow * BK);
    const int sw = (srow & 7) << 4;
#pragma unroll
    for (int h = hb; h < hb + 2; ++h) {
      uint4 wv;
      wv.x = pk2(xs * er[h * 8 + 0], xs * er[h * 8 + 1]);
      wv.y = pk2(xs * er[h * 8 + 2], xs * er[h * 8 + 3]);
      wv.z = pk2(xs * er[h * 8 + 4], xs * er[h * 8 + 5]);
      wv.w = pk2(xs * er[h * 8 + 6], xs * er[h * 8 + 7]);
      *(uint4*)(rowp + (((half * 64 + h * 16)) ^ sw)) = wv;
    }
  };
  auto rdA = [&](const unsigned short* Ab, int ks, int fr) -> short8 {
    const int row = wr * 112 + fr * 16 + l15;
    return *(const short8*)((const char*)Ab + row * 128 + ((ks * 64 + kb0) ^ sx));
  };
  auto rdB = [&](const unsigned short* Bb, int ks, int fc) -> short8 {
    const int row = wc * 64 + fc * 16 + l15;
    return *(const short8*)((const char*)Bb + row * 128 + ((ks * 64 + kb0) ^ sx));
  };

  // mode bits: 1 = stage A(t+1) with scale xs, 2 = stage B(t+2)
  auto tileF = [&](int t, float xs, int mode, int apar, int cb) {
    const unsigned short* Ac = Al[apar];
    unsigned short*       Aw = Al[apar ^ 1];
    const unsigned short* Bc = Bl[cb];
    unsigned short*       Bw = Bl[cb >= 1 ? cb - 1 : 2];   // (cb+2)%3

    short8 af0[4], af1[3], bfv[4];

    // ---- P1: ks0 reads (8) + first half of B(t+2) ----
#pragma unroll
    for (int fr = 0; fr < 4; ++fr) af0[fr] = rdA(Ac, 0, fr);
#pragma unroll
    for (int fc = 0; fc < 4; ++fc) bfv[fc] = rdB(Bc, 0, fc);
    if (mode & 2) issueB2(Bw, t + 2, 0);
    __builtin_amdgcn_s_barrier();
    asm volatile("s_waitcnt lgkmcnt(0)" ::: "memory");
    __builtin_amdgcn_s_setprio(1);
#pragma unroll
    for (int fr = 0; fr < 4; ++fr)
#pragma unroll
      for (int fc = 0; fc < 4; ++fc)
        acc[fr][fc] = __builtin_amdgcn_mfma_f32_16x16x32_bf16(af0[fr], bfv[fc],
                                                              acc[fr][fc], 0, 0, 0);
    __builtin_amdgcn_s_setprio(0);
    __builtin_amdgcn_s_barrier();

    // ---- P2: ks0 tail rows (3) + second half of B(t+2) ----
#pragma unroll
    for (int fr = 0; fr < 3; ++fr) af1[fr] = rdA(Ac, 0, 4 + fr);
    if (mode & 2) issueB2(Bw, t + 2, 2);
    __builtin_amdgcn_s_barrier();
    asm volatile("s_waitcnt lgkmcnt(0)" ::: "memory");
    __builtin_amdgcn_s_setprio(1);
#pragma unroll
    for (int fr = 0; fr < 3; ++fr)
#pragma unroll
      for (int fc = 0; fc < 4; ++fc)
        acc[4 + fr][fc] = __builtin_amdgcn_mfma_f32_16x16x32_bf16(af1[fr], bfv[fc],
                                                                  acc[4 + fr][fc], 0, 0, 0);
    __builtin_amdgcn_s_setprio(0);
    __builtin_amdgcn_s_barrier();

    // ---- P3: ks1 reads (8) + A(t+1) first half ----
#pragma unroll
    for (int fr = 0; fr < 4; ++fr) af0[fr] = rdA(Ac, 1, fr);
#pragma unroll
    for (int fc = 0; fc < 4; ++fc) bfv[fc] = rdB(Bc, 1, fc);
    if (mode & 1) stageA2(Aw, xs, 0);
    __builtin_amdgcn_s_barrier();
    asm volatile("s_waitcnt lgkmcnt(0)" ::: "memory");
    __builtin_amdgcn_s_setprio(1);
#pragma unroll
    for (int fr = 0; fr < 4; ++fr)
#pragma unroll
      for (int fc = 0; fc < 4; ++fc)
        acc[fr][fc] = __builtin_amdgcn_mfma_f32_16x16x32_bf16(af0[fr], bfv[fc],
                                                              acc[fr][fc], 0, 0, 0);
    __builtin_amdgcn_s_setprio(0);
    __builtin_amdgcn_s_barrier();

    // ---- P4: ks1 tail rows (3) + A(t+1) second half; publish waits ----
#pragma unroll
    for (int fr = 0; fr < 3; ++fr) af1[fr] = rdA(Ac, 1, 4 + fr);
    if (mode & 1) stageA2(Aw, xs, 2);
    asm volatile("s_waitcnt lgkmcnt(0)" ::: "memory");   // own A-writes + reads drained
    if (mode & 2) {
      asm volatile("s_waitcnt vmcnt(4)" ::: "memory");   // B(t+1) done; B(t+2) in flight
    } else {
      asm volatile("s_waitcnt vmcnt(0)" ::: "memory");   // tail tiles
    }
    __builtin_amdgcn_s_barrier();
    __builtin_amdgcn_s_setprio(1);
#pragma unroll
    for (int fr = 0; fr < 3; ++fr)
#pragma unroll
      for (int fc = 0; fc < 4; ++fc)
        acc[4 + fr][fc] = __builtin_amdgcn_mfma_f32_16x16x32_bf16(af1[fr], bfv[fc],
                                                                  acc[4 + fr][fc], 0, 0, 0);
    __builtin_amdgcn_s_setprio(0);
    __builtin_amdgcn_s_barrier();   // closing barrier: t+1 buffers published
  };

  // ---- prologue: x[0..3], A(0)->Al[0], B(0)->Bl[0], B(1)->Bl[1] ----
  float4 xv = stA ? *(const float4*)xrow : make_float4(0.f, 0.f, 0.f, 0.f);
  stageA2(Al[0], xv.x, 0);
  stageA2(Al[0], xv.x, 2);
  issueB2(Bl[0], 0, 0); issueB2(Bl[0], 0, 2);
  issueB2(Bl[1], 1, 0); issueB2(Bl[1], 1, 2);
  asm volatile("s_waitcnt lgkmcnt(0)" ::: "memory");
  asm volatile("s_waitcnt vmcnt(4)" ::: "memory");       // B(0) resident, B(1) in flight
  __builtin_amdgcn_s_barrier();

  int cb = 0;
  for (int u = 0; u < 32; ++u) {
    float4 xvn = xv;
    if (stA && u < 31) xvn = *(const float4*)(xrow + (u + 1) * 4);
    const int t0 = u * 4;
    tileF(t0 + 0, xv.y, 3, 0, cb); cb = (cb == 2) ? 0 : cb + 1;
    tileF(t0 + 1, xv.z, 3, 1, cb); cb = (cb == 2) ? 0 : cb + 1;
    tileF(t0 + 2, xv.w, 3, 0, cb); cb = (cb == 2) ? 0 : cb + 1;
    if (u < 31) {
      tileF(t0 + 3, xvn.x, 3, 1, cb);
    } else {   // t=127: stage bias tile A(128) = er (half0) / 0 (half1); no B(129)
      tileF(t0 + 3, half ? 0.f : 1.f, 1, 1, cb);
    }
    cb = (cb == 2) ? 0 : cb + 1;
    xv = xvn;
  }
  tileF(128, 0.f, 0, 0, cb);   // bias tile: no staging, vmcnt(0) free

  // ---- epilogue: C layout col = lane&15, row = (lane>>4)*4 + j ----
#pragma unroll
  for (int fr = 0; fr < 7; ++fr) {
    const int r0 = m0 + wr * 112 + fr * 16 + (lane >> 4) * 4;
#pragma unroll
    for (int j = 0; j < 4; ++j) {
      const int rr = r0 + j;
      if (rr < Ntot) {
#pragma unroll
        for (int fc = 0; fc < 4; ++fc) {
          const int col = wc * 64 + fc * 16 + l15;
          out[(size_t)rr * O_DIM + col] = acc[fr][fc][j];
        }
      }
    }
  }
}

// ---- fallback (ws too small): simple 2-barrier kernel reading W/b directly ----
__global__ __launch_bounds__(256) void lkg_fb(
    const float* __restrict__ x, const float* __restrict__ e,
    const float* __restrict__ Wf, const float* __restrict__ bf32,
    float* __restrict__ out, int Ntot) {
  const int FBK = 64;
  const int FNT = (KW + 64) / FBK;
  __shared__ unsigned short Alds[128 * 64];
  __shared__ unsigned short Blds[256 * 64];

  const int tid = threadIdx.x, lane = tid & 63, wid = tid >> 6;
  const int wr = wid >> 1, wc = wid & 1, l15 = lane & 15, lk8 = (lane >> 4) * 8;
  const int m0 = (int)blockIdx.x * 128;
  const int srow = tid >> 1, skq = (tid & 1) * 32;
  const int gr = min(m0 + srow, Ntot - 1);

  f32x4 acc[4][8];
#pragma unroll
  for (int a = 0; a < 4; ++a)
#pragma unroll
    for (int c = 0; c < 8; ++c) acc[a][c] = (f32x4){0.f, 0.f, 0.f, 0.f};

  for (int t = 0; t < FNT; ++t) {
    const int k0 = t * FBK;
    float av[32];
    if (k0 < KW) {
      const int r = k0 >> 8, i0 = k0 & 255;
      const float ev = e[(size_t)gr * R_DIM + r];
#pragma unroll
      for (int q = 0; q < 8; ++q) {
        const float4 xvv = *(const float4*)&x[(size_t)gr * I_DIM + i0 + skq + q * 4];
        av[q * 4 + 0] = xvv.x * ev; av[q * 4 + 1] = xvv.y * ev;
        av[q * 4 + 2] = xvv.z * ev; av[q * 4 + 3] = xvv.w * ev;
      }
    } else {
#pragma unroll
      for (int s2 = 0; s2 < 32; ++s2) {
        const int kk = skq + s2;
        av[s2] = (kk < R_DIM) ? e[(size_t)gr * R_DIM + kk] : 0.f;
      }
    }
    const int bo = tid;
    if (k0 < KW) {
      const int r = k0 >> 8, i0 = k0 & 255;
#pragma unroll
      for (int h = 0; h < 4; ++h) {
        float bv[16];
#pragma unroll
        for (int q = 0; q < 4; ++q) {
          const float4 wv =
              *(const float4*)&Wf[((size_t)(r * O_DIM + bo)) * I_DIM + i0 + h * 16 + q * 4];
          bv[q * 4 + 0] = wv.x; bv[q * 4 + 1] = wv.y;
          bv[q * 4 + 2] = wv.z; bv[q * 4 + 3] = wv.w;
        }
#pragma unroll
        for (int g2 = 0; g2 < 2; ++g2) {
          ushort8 pw;
#pragma unroll
          for (int j = 0; j < 8; ++j) pw[j] = f2bf(bv[g2 * 8 + j]);
          *(ushort8*)&Blds[bo * FBK + h * 16 + g2 * 8] = pw;
        }
      }
    } else {
#pragma unroll
      for (int h = 0; h < 8; ++h) {
        ushort8 pw;
#pragma unroll
        for (int j = 0; j < 8; ++j) {
          const int kk = h * 8 + j;
          pw[j] = (kk < R_DIM) ? f2bf(bf32[kk * O_DIM + bo]) : (unsigned short)0;
        }
        *(ushort8*)&Blds[bo * FBK + h * 8] = pw;
      }
    }
#pragma unroll
    for (int h = 0; h < 4; ++h) {
      ushort8 pw;
#pragma unroll
      for (int j = 0; j < 8; ++j) pw[j] = f2bf(av[h * 8 + j]);
      *(ushort8*)&Alds[srow * FBK + skq + h * 8] = pw;
    }
    __syncthreads();
#pragma unroll
    for (int ks = 0; ks < 2; ++ks) {
      short8 af[4]; short8 bfr[8];
#pragma unroll
      for (int fr = 0; fr < 4; ++fr)
        af[fr] = *(const short8*)&Alds[(wr * 64 + fr * 16 + l15) * FBK + ks * 32 + lk8];
#pragma unroll
      for (int fc = 0; fc < 8; ++fc)
        bfr[fc] = *(const short8*)&Blds[(wc * 128 + fc * 16 + l15) * FBK + ks * 32 + lk8];
#pragma unroll
      for (int fr = 0; fr < 4; ++fr)
#pragma unroll
        for (int fc = 0; fc < 8; ++fc)
          acc[fr][fc] =
              __builtin_amdgcn_mfma_f32_16x16x32_bf16(af[fr], bfr[fc], acc[fr][fc], 0, 0, 0);
    }
    __syncthreads();
  }
#pragma unroll
  for (int fr = 0; fr < 4; ++fr) {
    const int r0 = m0 + wr * 64 + fr * 16 + (lane >> 4) * 4;
#pragma unroll
    for (int fc = 0; fc < 8; ++fc) {
      const int col = wc * 128 + fc * 16 + l15;
#pragma unroll
      for (int j = 0; j < 4; ++j) {
        const int rr = r0 + j;
        if (rr < Ntot) out[(size_t)rr * O_DIM + col] = acc[fr][fc][j];
      }
    }
  }
}

extern "C" void kernel_launch(void* const* d_in, const int* in_sizes, int n_in,
                              void* d_out, int out_size, void* d_ws, size_t ws_size,
                              hipStream_t stream) {
  const float* x = (const float*)d_in[0];
  const float* e = (const float*)d_in[1];
  const float* W = (const float*)d_in[2];
  const float* b = (const float*)d_in[3];
  float* out = (float*)d_out;
  const int Ntot = in_sizes[0] / I_DIM;

  const size_t wb_bytes = (size_t)O_DIM * KEXT * sizeof(unsigned short);
  if (ws_size >= wb_bytes) {
    unsigned short* Wb = (unsigned short*)d_ws;
    prep_w<<<(O_DIM * (KEXT / 4)) / 256, 256, 0, stream>>>(W, b, Wb);
    lkg8q<<<(Ntot + BM - 1) / BM, NTHR, 0, stream>>>(x, e, Wb, out, Ntot);
  } else {
    lkg_fb<<<(Ntot + 127) / 128, 256, 0, stream>>>(x, e, W, b, out, Ntot);
  }
}

// Round 7
// 1971.395 us; speedup vs baseline: 1.1610x; 1.1610x over previous
//
#include <hip/hip_runtime.h>
#include <hip/hip_bf16.h>

// y[n,o] = sum_r e[n,r]*(W[r]@x[n])[o] + (e@b)[n,o]
// One bf16 GEMM, K = 8256: k = il*64 + ih*32 + r (i = 128*ih + il), bias tile appended.
// A'[n,k] = e[n,r]*x[n,i] built on the fly. Thread covers r-half (er[16] in regs),
// both i-halves via two x float4 streams. B^T = Wb[o][k] bf16 in d_ws; LDS XOR-swizzled
// (A: swizzled ds_write; B: pre-swizzled gld_lds source). 4 phases/K-tile, counted
// vmcnt(4), setprio, tri-buffered B. amdgpu_waves_per_eu(2,2) pins the 256-reg budget
// (R4/R6: allocator chose 128 and spilled acc -> 2.9GB/847MB scratch traffic).

typedef __attribute__((ext_vector_type(4))) float f32x4;
typedef __attribute__((ext_vector_type(8))) short short8;
typedef __attribute__((ext_vector_type(8))) unsigned short ushort8;

#define R_DIM 32
#define I_DIM 256
#define O_DIM 256
#define KW    8192
#define KEXT  8256            // +64: [8192,8224)=b^T, rest 0
#define BM    224
#define BN    256
#define BK    64
#define NT    (KEXT / BK)     // 129
#define NTHR  512

__device__ __forceinline__ unsigned short f2bf(float f) {
  unsigned u = __builtin_bit_cast(unsigned, f);
  u += 0x7FFFu + ((u >> 16) & 1u);  // RNE
  return (unsigned short)(u >> 16);
}

__device__ __forceinline__ unsigned pk2(float a, float b) {
  __hip_bfloat162 h = __float22bfloat162_rn(make_float2(a, b));  // v_cvt_pk_bf16_f32, RNE
  unsigned u;
  __builtin_memcpy(&u, &h, sizeof(u));
  return u;
}

__device__ __forceinline__ void gld_lds16(const void* g, void* l) {
  __builtin_amdgcn_global_load_lds(
      (const __attribute__((address_space(1))) unsigned int*)g,
      (__attribute__((address_space(3))) unsigned int*)l, 16, 0, 0);
}

// ---- prep: Wb[o][k] = bf16(W[r,o,i]), k = il*64+ih*32+r, i = 128*ih+il ----
__global__ void prep_w(const float* __restrict__ W, const float* __restrict__ b,
                       unsigned short* __restrict__ Wb) {
  const int id = blockIdx.x * 256 + threadIdx.x;   // 256 * 2064 threads exactly
  const int o  = id / (KEXT / 4);
  const int k4 = (id - o * (KEXT / 4)) * 4;
  float v[4];
  if (k4 < KW) {
    const int r  = k4 & 31;
    const int ih = (k4 >> 5) & 1;
    const int il = k4 >> 6;
    const int i  = 128 * ih + il;
#pragma unroll
    for (int j = 0; j < 4; ++j)
      v[j] = W[((size_t)((r + j) * O_DIM + o)) * I_DIM + i];
  } else {
    const int kk = k4 - KW;
#pragma unroll
    for (int j = 0; j < 4; ++j)
      v[j] = (kk + j < R_DIM) ? b[(kk + j) * O_DIM + o] : 0.f;
  }
  uint2 pk;
  pk.x = pk2(v[0], v[1]);
  pk.y = pk2(v[2], v[3]);
  *(uint2*)&Wb[(size_t)o * KEXT + k4] = pk;
}

// ---- main: 512 thr, 8 waves (2M x 4N), wave tile 112x64, 4-phase counted-vmcnt ----
__global__ __launch_bounds__(NTHR)
__attribute__((amdgpu_waves_per_eu(2, 2)))
void lkg8r(
    const float* __restrict__ x, const float* __restrict__ e,
    const unsigned short* __restrict__ Wb, float* __restrict__ out, int Ntot) {
  __shared__ unsigned short Al[2][BM * BK];   // 2 x 28 KB
  __shared__ unsigned short Bl[3][BN * BK];   // 3 x 32 KB  (152 KB total)

  const int tid  = threadIdx.x;
  const int lane = tid & 63;
  const int w    = tid >> 6;     // 0..7
  const int wr   = w >> 2;       // 0..1
  const int wc   = w & 3;        // 0..3
  const int l15  = lane & 15;
  const int sx   = (l15 & 7) << 4;
  const int kb0  = (lane >> 4) << 4;

  const int  m0   = (int)blockIdx.x * BM;
  const bool stA  = (tid < 2 * BM);        // waves 0..6 stage A
  const int  srow = tid >> 1;              // 0..223
  const int  half = tid & 1;               // r-half of this thread
  const int  gr   = min(m0 + (stA ? srow : 0), Ntot - 1);

  // B gld_lds source-side swizzle (rule #21: linear dest + inverse-swz source)
  const int bro = lane >> 3;              // row within 8-row group
  const int bch = (lane & 7) ^ bro;       // pre-swizzled chunk index

  // e r-half cached in registers: er[j] = e[gr, half*16 + j], j = 0..15
  float er[16];
  if (stA) {
#pragma unroll
    for (int q = 0; q < 4; ++q) {
      const float4 ev = *(const float4*)&e[(size_t)gr * R_DIM + half * 16 + q * 4];
      er[q * 4 + 0] = ev.x; er[q * 4 + 1] = ev.y;
      er[q * 4 + 2] = ev.z; er[q * 4 + 3] = ev.w;
    }
  }
  const float* xr0 = x + (size_t)gr * I_DIM;        // i-half 0 stream
  const float* xr1 = x + (size_t)gr * I_DIM + 128;  // i-half 1 stream

  f32x4 acc[7][4];
#pragma unroll
  for (int a = 0; a < 7; ++a)
#pragma unroll
    for (int c = 0; c < 4; ++c) acc[a][c] = (f32x4){0.f, 0.f, 0.f, 0.f};

  auto issueB2 = [&](unsigned short* Bd, int t2, int gb) {
    const size_t k0 = (size_t)t2 * BK;
#pragma unroll
    for (int g = gb; g < gb + 2; ++g)
      gld_lds16(Wb + (size_t)(w * 32 + g * 8 + bro) * KEXT + k0 + bch * 8,
                Bd + (w * 32 + g * 8) * BK);
  };
  // stage this thread's r-half for i-half ih: bytes (ih*64 + half*32 + {0,16}) ^ sw
  auto stageAih = [&](unsigned short* Ad, float xs, int ih) {
    if (!stA) return;
    char* rowp = (char*)(Ad + srow * BK);
    const int sw = (srow & 7) << 4;
    const int base = ih * 64 + half * 32;
    uint4 wv;
    wv.x = pk2(xs * er[0], xs * er[1]);
    wv.y = pk2(xs * er[2], xs * er[3]);
    wv.z = pk2(xs * er[4], xs * er[5]);
    wv.w = pk2(xs * er[6], xs * er[7]);
    *(uint4*)(rowp + ((base + 0) ^ sw)) = wv;
    uint4 wv2;
    wv2.x = pk2(xs * er[8],  xs * er[9]);
    wv2.y = pk2(xs * er[10], xs * er[11]);
    wv2.z = pk2(xs * er[12], xs * er[13]);
    wv2.w = pk2(xs * er[14], xs * er[15]);
    *(uint4*)(rowp + ((base + 16) ^ sw)) = wv2;
  };
  auto rdA = [&](const unsigned short* Ab, int ks, int fr) -> short8 {
    const int row = wr * 112 + fr * 16 + l15;
    return *(const short8*)((const char*)Ab + row * 128 + ((ks * 64 + kb0) ^ sx));
  };
  auto rdB = [&](const unsigned short* Bb, int ks, int fc) -> short8 {
    const int row = wc * 64 + fc * 16 + l15;
    return *(const short8*)((const char*)Bb + row * 128 + ((ks * 64 + kb0) ^ sx));
  };

  // mode bits: 1 = stage A(t+1) with scales xs0/xs1, 2 = stage B(t+2)
  auto tileF = [&](int t, float xs0, float xs1, int mode, int apar, int cb) {
    const unsigned short* Ac = Al[apar];
    unsigned short*       Aw = Al[apar ^ 1];
    const unsigned short* Bc = Bl[cb];
    unsigned short*       Bw = Bl[cb >= 1 ? cb - 1 : 2];   // (cb+2)%3

    short8 af0[4], af1[3], bfv[4];

    // ---- P1: ks0 reads (8) + first half of B(t+2) ----
#pragma unroll
    for (int fr = 0; fr < 4; ++fr) af0[fr] = rdA(Ac, 0, fr);
#pragma unroll
    for (int fc = 0; fc < 4; ++fc) bfv[fc] = rdB(Bc, 0, fc);
    if (mode & 2) issueB2(Bw, t + 2, 0);
    __builtin_amdgcn_s_barrier();
    asm volatile("s_waitcnt lgkmcnt(0)" ::: "memory");
    __builtin_amdgcn_s_setprio(1);
#pragma unroll
    for (int fr = 0; fr < 4; ++fr)
#pragma unroll
      for (int fc = 0; fc < 4; ++fc)
        acc[fr][fc] = __builtin_amdgcn_mfma_f32_16x16x32_bf16(af0[fr], bfv[fc],
                                                              acc[fr][fc], 0, 0, 0);
    __builtin_amdgcn_s_setprio(0);
    __builtin_amdgcn_s_barrier();

    // ---- P2: ks0 tail rows (3) + second half of B(t+2) ----
#pragma unroll
    for (int fr = 0; fr < 3; ++fr) af1[fr] = rdA(Ac, 0, 4 + fr);
    if (mode & 2) issueB2(Bw, t + 2, 2);
    __builtin_amdgcn_s_barrier();
    asm volatile("s_waitcnt lgkmcnt(0)" ::: "memory");
    __builtin_amdgcn_s_setprio(1);
#pragma unroll
    for (int fr = 0; fr < 3; ++fr)
#pragma unroll
      for (int fc = 0; fc < 4; ++fc)
        acc[4 + fr][fc] = __builtin_amdgcn_mfma_f32_16x16x32_bf16(af1[fr], bfv[fc],
                                                                  acc[4 + fr][fc], 0, 0, 0);
    __builtin_amdgcn_s_setprio(0);
    __builtin_amdgcn_s_barrier();

    // ---- P3: ks1 reads (8) + A(t+1) i-half 0 ----
#pragma unroll
    for (int fr = 0; fr < 4; ++fr) af0[fr] = rdA(Ac, 1, fr);
#pragma unroll
    for (int fc = 0; fc < 4; ++fc) bfv[fc] = rdB(Bc, 1, fc);
    if (mode & 1) stageAih(Aw, xs0, 0);
    __builtin_amdgcn_s_barrier();
    asm volatile("s_waitcnt lgkmcnt(0)" ::: "memory");
    __builtin_amdgcn_s_setprio(1);
#pragma unroll
    for (int fr = 0; fr < 4; ++fr)
#pragma unroll
      for (int fc = 0; fc < 4; ++fc)
        acc[fr][fc] = __builtin_amdgcn_mfma_f32_16x16x32_bf16(af0[fr], bfv[fc],
                                                              acc[fr][fc], 0, 0, 0);
    __builtin_amdgcn_s_setprio(0);
    __builtin_amdgcn_s_barrier();

    // ---- P4: ks1 tail rows (3) + A(t+1) i-half 1; publish waits ----
#pragma unroll
    for (int fr = 0; fr < 3; ++fr) af1[fr] = rdA(Ac, 1, 4 + fr);
    if (mode & 1) stageAih(Aw, xs1, 1);
    asm volatile("s_waitcnt lgkmcnt(0)" ::: "memory");   // own A-writes + reads drained
    if (mode & 2) {
      asm volatile("s_waitcnt vmcnt(4)" ::: "memory");   // B(t+1) done; B(t+2) in flight
    } else {
      asm volatile("s_waitcnt vmcnt(0)" ::: "memory");   // tail tiles
    }
    __builtin_amdgcn_s_barrier();
    __builtin_amdgcn_s_setprio(1);
#pragma unroll
    for (int fr = 0; fr < 3; ++fr)
#pragma unroll
      for (int fc = 0; fc < 4; ++fc)
        acc[4 + fr][fc] = __builtin_amdgcn_mfma_f32_16x16x32_bf16(af1[fr], bfv[fc],
                                                                  acc[4 + fr][fc], 0, 0, 0);
    __builtin_amdgcn_s_setprio(0);
    __builtin_amdgcn_s_barrier();   // closing barrier: t+1 buffers published
  };

  // ---- prologue: A(0)->Al[0], B(0)->Bl[0], B(1)->Bl[1] ----
  float4 xv0 = stA ? *(const float4*)xr0 : make_float4(0.f, 0.f, 0.f, 0.f);
  float4 xv1 = stA ? *(const float4*)xr1 : make_float4(0.f, 0.f, 0.f, 0.f);
  stageAih(Al[0], xv0.x, 0);
  stageAih(Al[0], xv1.x, 1);
  issueB2(Bl[0], 0, 0); issueB2(Bl[0], 0, 2);
  issueB2(Bl[1], 1, 0); issueB2(Bl[1], 1, 2);
  asm volatile("s_waitcnt lgkmcnt(0)" ::: "memory");
  asm volatile("s_waitcnt vmcnt(4)" ::: "memory");       // B(0) resident, B(1) in flight
  __builtin_amdgcn_s_barrier();

  int cb = 0;
  for (int u = 0; u < 32; ++u) {
    float4 xn0 = xv0, xn1 = xv1;
    if (stA && u < 31) {
      xn0 = *(const float4*)(xr0 + (u + 1) * 4);
      xn1 = *(const float4*)(xr1 + (u + 1) * 4);
    }
    const int t0 = u * 4;
    tileF(t0 + 0, xv0.y, xv1.y, 3, 0, cb); cb = (cb == 2) ? 0 : cb + 1;
    tileF(t0 + 1, xv0.z, xv1.z, 3, 1, cb); cb = (cb == 2) ? 0 : cb + 1;
    tileF(t0 + 2, xv0.w, xv1.w, 3, 0, cb); cb = (cb == 2) ? 0 : cb + 1;
    if (u < 31) {
      tileF(t0 + 3, xn0.x, xn1.x, 3, 1, cb);
    } else {   // t=127: stage bias tile A(128): ih0 = er, ih1 = 0
      tileF(t0 + 3, 1.f, 0.f, 1, 1, cb);
    }
    cb = (cb == 2) ? 0 : cb + 1;
    xv0 = xn0; xv1 = xn1;
  }
  tileF(128, 0.f, 0.f, 0, 0, cb);   // bias tile: no staging, vmcnt(0) free

  // ---- epilogue: C layout col = lane&15, row = (lane>>4)*4 + j ----
#pragma unroll
  for (int fr = 0; fr < 7; ++fr) {
    const int r0 = m0 + wr * 112 + fr * 16 + (lane >> 4) * 4;
#pragma unroll
    for (int j = 0; j < 4; ++j) {
      const int rr = r0 + j;
      if (rr < Ntot) {
#pragma unroll
        for (int fc = 0; fc < 4; ++fc) {
          const int col = wc * 64 + fc * 16 + l15;
          out[(size_t)rr * O_DIM + col] = acc[fr][fc][j];
        }
      }
    }
  }
}

// ---- fallback (ws too small): simple 2-barrier kernel reading W/b directly ----
__global__ __launch_bounds__(256) void lkg_fb(
    const float* __restrict__ x, const float* __restrict__ e,
    const float* __restrict__ Wf, const float* __restrict__ bf32,
    float* __restrict__ out, int Ntot) {
  const int FBK = 64;
  const int FNT = (KW + 64) / FBK;
  __shared__ unsigned short Alds[128 * 64];
  __shared__ unsigned short Blds[256 * 64];

  const int tid = threadIdx.x, lane = tid & 63, wid = tid >> 6;
  const int wr = wid >> 1, wc = wid & 1, l15 = lane & 15, lk8 = (lane >> 4) * 8;
  const int m0 = (int)blockIdx.x * 128;
  const int srow = tid >> 1, skq = (tid & 1) * 32;
  const int gr = min(m0 + srow, Ntot - 1);

  f32x4 acc[4][8];
#pragma unroll
  for (int a = 0; a < 4; ++a)
#pragma unroll
    for (int c = 0; c < 8; ++c) acc[a][c] = (f32x4){0.f, 0.f, 0.f, 0.f};

  for (int t = 0; t < FNT; ++t) {
    const int k0 = t * FBK;
    float av[32];
    if (k0 < KW) {
      const int r = k0 >> 8, i0 = k0 & 255;
      const float ev = e[(size_t)gr * R_DIM + r];
#pragma unroll
      for (int q = 0; q < 8; ++q) {
        const float4 xvv = *(const float4*)&x[(size_t)gr * I_DIM + i0 + skq + q * 4];
        av[q * 4 + 0] = xvv.x * ev; av[q * 4 + 1] = xvv.y * ev;
        av[q * 4 + 2] = xvv.z * ev; av[q * 4 + 3] = xvv.w * ev;
      }
    } else {
#pragma unroll
      for (int s2 = 0; s2 < 32; ++s2) {
        const int kk = skq + s2;
        av[s2] = (kk < R_DIM) ? e[(size_t)gr * R_DIM + kk] : 0.f;
      }
    }
    const int bo = tid;
    if (k0 < KW) {
      const int r = k0 >> 8, i0 = k0 & 255;
#pragma unroll
      for (int h = 0; h < 4; ++h) {
        float bv[16];
#pragma unroll
        for (int q = 0; q < 4; ++q) {
          const float4 wv =
              *(const float4*)&Wf[((size_t)(r * O_DIM + bo)) * I_DIM + i0 + h * 16 + q * 4];
          bv[q * 4 + 0] = wv.x; bv[q * 4 + 1] = wv.y;
          bv[q * 4 + 2] = wv.z; bv[q * 4 + 3] = wv.w;
        }
#pragma unroll
        for (int g2 = 0; g2 < 2; ++g2) {
          ushort8 pw;
#pragma unroll
          for (int j = 0; j < 8; ++j) pw[j] = f2bf(bv[g2 * 8 + j]);
          *(ushort8*)&Blds[bo * FBK + h * 16 + g2 * 8] = pw;
        }
      }
    } else {
#pragma unroll
      for (int h = 0; h < 8; ++h) {
        ushort8 pw;
#pragma unroll
        for (int j = 0; j < 8; ++j) {
          const int kk = h * 8 + j;
          pw[j] = (kk < R_DIM) ? f2bf(bf32[kk * O_DIM + bo]) : (unsigned short)0;
        }
        *(ushort8*)&Blds[bo * FBK + h * 8] = pw;
      }
    }
#pragma unroll
    for (int h = 0; h < 4; ++h) {
      ushort8 pw;
#pragma unroll
      for (int j = 0; j < 8; ++j) pw[j] = f2bf(av[h * 8 + j]);
      *(ushort8*)&Alds[srow * FBK + skq + h * 8] = pw;
    }
    __syncthreads();
#pragma unroll
    for (int ks = 0; ks < 2; ++ks) {
      short8 af[4]; short8 bfr[8];
#pragma unroll
      for (int fr = 0; fr < 4; ++fr)
        af[fr] = *(const short8*)&Alds[(wr * 64 + fr * 16 + l15) * FBK + ks * 32 + lk8];
#pragma unroll
      for (int fc = 0; fc < 8; ++fc)
        bfr[fc] = *(const short8*)&Blds[(wc * 128 + fc * 16 + l15) * FBK + ks * 32 + lk8];
#pragma unroll
      for (int fr = 0; fr < 4; ++fr)
#pragma unroll
        for (int fc = 0; fc < 8; ++fc)
          acc[fr][fc] =
              __builtin_amdgcn_mfma_f32_16x16x32_bf16(af[fr], bfr[fc], acc[fr][fc], 0, 0, 0);
    }
    __syncthreads();
  }
#pragma unroll
  for (int fr = 0; fr < 4; ++fr) {
    const int r0 = m0 + wr * 64 + fr * 16 + (lane >> 4) * 4;
#pragma unroll
    for (int fc = 0; fc < 8; ++fc) {
      const int col = wc * 128 + fc * 16 + l15;
#pragma unroll
      for (int j = 0; j < 4; ++j) {
        const int rr = r0 + j;
        if (rr < Ntot) out[(size_t)rr * O_DIM + col] = acc[fr][fc][j];
      }
    }
  }
}

extern "C" void kernel_launch(void* const* d_in, const int* in_sizes, int n_in,
                              void* d_out, int out_size, void* d_ws, size_t ws_size,
                              hipStream_t stream) {
  const float* x = (const float*)d_in[0];
  const float* e = (const float*)d_in[1];
  const float* W = (const float*)d_in[2];
  const float* b = (const float*)d_in[3];
  float* out = (float*)d_out;
  const int Ntot = in_sizes[0] / I_DIM;

  const size_t wb_bytes = (size_t)O_DIM * KEXT * sizeof(unsigned short);
  if (ws_size >= wb_bytes) {
    unsigned short* Wb = (unsigned short*)d_ws;
    prep_w<<<(O_DIM * (KEXT / 4)) / 256, 256, 0, stream>>>(W, b, Wb);
    lkg8r<<<(Ntot + BM - 1) / BM, NTHR, 0, stream>>>(x, e, Wb, out, Ntot);
  } else {
    lkg_fb<<<(Ntot + 127) / 128, 256, 0, stream>>>(x, e, W, b, out, Ntot);
  }
}

// Round 8
// 607.252 us; speedup vs baseline: 3.7692x; 3.2464x over previous
//
#include <hip/hip_runtime.h>
#include <hip/hip_bf16.h>

// y[n,o] = sum_r e[n,r]*(W[r]@x[n])[o] + (e@b)[n,o]
// One bf16 GEMM, K = 8256: k = il*64 + ih*32 + r (i = 128*ih + il), bias tile appended.
// Tile t == il. A'[n,k] = e[n,r]*x[n,i] staged on the fly: thread covers 16 cols
// (q = tid&3 -> ih = q>>1, r-half = q&1), er[16] in regs, one x scalar per tile.
// B^T = Wb[o][k] bf16 in d_ws; LDS XOR-swizzled (A: swizzled ds_write; B: pre-swizzled
// gld_lds source). 2 phases/K-tile (16 MFMA each), counted vmcnt(4), setprio,
// A dbuf + B tri-buf (128 KB). Wave tile 64x64 -> acc=64 AGPR so arch regs fit the
// 256-unified budget at 2 waves/SIMD (R4/R6/R7 lesson: acc=112 + 4-phase frags MUST spill).

typedef __attribute__((ext_vector_type(4))) float f32x4;
typedef __attribute__((ext_vector_type(8))) short short8;
typedef __attribute__((ext_vector_type(8))) unsigned short ushort8;

#define R_DIM 32
#define I_DIM 256
#define O_DIM 256
#define KW    8192
#define KEXT  8256            // +64: [8192,8224)=b^T, rest 0
#define BM    128
#define BN    256
#define BK    64
#define NT    (KEXT / BK)     // 129
#define NTHR  512

__device__ __forceinline__ unsigned short f2bf(float f) {
  unsigned u = __builtin_bit_cast(unsigned, f);
  u += 0x7FFFu + ((u >> 16) & 1u);  // RNE
  return (unsigned short)(u >> 16);
}

__device__ __forceinline__ unsigned pk2(float a, float b) {
  __hip_bfloat162 h = __float22bfloat162_rn(make_float2(a, b));  // v_cvt_pk_bf16_f32, RNE
  unsigned u;
  __builtin_memcpy(&u, &h, sizeof(u));
  return u;
}

__device__ __forceinline__ void gld_lds16(const void* g, void* l) {
  __builtin_amdgcn_global_load_lds(
      (const __attribute__((address_space(1))) unsigned int*)g,
      (__attribute__((address_space(3))) unsigned int*)l, 16, 0, 0);
}

// ---- prep: Wb[o][k] = bf16(W[r,o,i]), k = il*64+ih*32+r, i = 128*ih+il ----
__global__ void prep_w(const float* __restrict__ W, const float* __restrict__ b,
                       unsigned short* __restrict__ Wb) {
  const int id = blockIdx.x * 256 + threadIdx.x;   // 256 * 2064 threads exactly
  const int o  = id / (KEXT / 4);
  const int k4 = (id - o * (KEXT / 4)) * 4;
  float v[4];
  if (k4 < KW) {
    const int r  = k4 & 31;
    const int ih = (k4 >> 5) & 1;
    const int il = k4 >> 6;
    const int i  = 128 * ih + il;
#pragma unroll
    for (int j = 0; j < 4; ++j)
      v[j] = W[((size_t)((r + j) * O_DIM + o)) * I_DIM + i];
  } else {
    const int kk = k4 - KW;
#pragma unroll
    for (int j = 0; j < 4; ++j)
      v[j] = (kk + j < R_DIM) ? b[(kk + j) * O_DIM + o] : 0.f;
  }
  uint2 pk;
  pk.x = pk2(v[0], v[1]);
  pk.y = pk2(v[2], v[3]);
  *(uint2*)&Wb[(size_t)o * KEXT + k4] = pk;
}

// ---- main: 512 thr, 8 waves (2M x 4N), wave tile 64x64, 2-phase counted-vmcnt ----
__global__ __launch_bounds__(NTHR)
__attribute__((amdgpu_waves_per_eu(2, 2)))
void lkg2p(
    const float* __restrict__ x, const float* __restrict__ e,
    const unsigned short* __restrict__ Wb, float* __restrict__ out, int Ntot) {
  __shared__ unsigned short Al[2][BM * BK];   // 2 x 16 KB
  __shared__ unsigned short Bl[3][BN * BK];   // 3 x 32 KB  (128 KB total)

  const int tid  = threadIdx.x;
  const int lane = tid & 63;
  const int w    = tid >> 6;     // 0..7
  const int wr   = w >> 2;       // 0..1  (M)
  const int wc   = w & 3;        // 0..3  (N)
  const int l15  = lane & 15;
  const int sx   = (l15 & 7) << 4;
  const int kb0  = (lane >> 4) << 4;

  const int m0   = (int)blockIdx.x * BM;
  const int srow = tid >> 2;               // 0..127: A row this thread stages
  const int q    = tid & 3;                // col quarter: ih = q>>1, r-half = q&1
  const int ih   = q >> 1;
  const int gr   = min(m0 + srow, Ntot - 1);

  // B gld_lds source-side swizzle (rule #21: linear dest + inverse-swz source)
  const int bro = lane >> 3;              // row within 8-row group
  const int bch = (lane & 7) ^ bro;       // pre-swizzled chunk index

  // e r-half in regs: er[j] = e[gr, (q&1)*16 + j]
  float er[16];
#pragma unroll
  for (int p = 0; p < 4; ++p) {
    const float4 ev = *(const float4*)&e[(size_t)gr * R_DIM + (q & 1) * 16 + p * 4];
    er[p * 4 + 0] = ev.x; er[p * 4 + 1] = ev.y;
    er[p * 4 + 2] = ev.z; er[p * 4 + 3] = ev.w;
  }
  const float* xrow = x + (size_t)gr * I_DIM + ih * 128;  // x scalar stream (il = t)
  const float bx = (ih == 0) ? 1.f : 0.f;                 // bias-tile scale

  f32x4 acc[4][4];
#pragma unroll
  for (int a = 0; a < 4; ++a)
#pragma unroll
    for (int c = 0; c < 4; ++c) acc[a][c] = (f32x4){0.f, 0.f, 0.f, 0.f};

  auto issueB4 = [&](unsigned short* Bd, int t2) {
    const size_t k0 = (size_t)t2 * BK;
#pragma unroll
    for (int g = 0; g < 4; ++g)
      gld_lds16(Wb + (size_t)(w * 32 + g * 8 + bro) * KEXT + k0 + bch * 8,
                Bd + (w * 32 + g * 8) * BK);
  };
  auto stageA = [&](unsigned short* Ad, float xs) {
    char* rowp = (char*)(Ad + srow * BK);
    const int sw = (srow & 7) << 4;
    const int qb = q * 32;
    uint4 wv;
    wv.x = pk2(xs * er[0], xs * er[1]);
    wv.y = pk2(xs * er[2], xs * er[3]);
    wv.z = pk2(xs * er[4], xs * er[5]);
    wv.w = pk2(xs * er[6], xs * er[7]);
    *(uint4*)(rowp + ((qb + 0) ^ sw)) = wv;
    uint4 wv2;
    wv2.x = pk2(xs * er[8],  xs * er[9]);
    wv2.y = pk2(xs * er[10], xs * er[11]);
    wv2.z = pk2(xs * er[12], xs * er[13]);
    wv2.w = pk2(xs * er[14], xs * er[15]);
    *(uint4*)(rowp + ((qb + 16) ^ sw)) = wv2;
  };
  auto rdA = [&](const unsigned short* Ab, int ks, int fr) -> short8 {
    const int row = wr * 64 + fr * 16 + l15;
    return *(const short8*)((const char*)Ab + row * 128 + ((ks * 64 + kb0) ^ sx));
  };
  auto rdB = [&](const unsigned short* Bb, int ks, int fc) -> short8 {
    const int row = wc * 64 + fc * 16 + l15;
    return *(const short8*)((const char*)Bb + row * 128 + ((ks * 64 + kb0) ^ sx));
  };

  // mode bits: 1 = stage A(t+1) with scale xs, 2 = issue B(t+2)
  auto tileF = [&](int t, float xs, int mode, int apar, int cb) {
    const unsigned short* Ac = Al[apar];
    unsigned short*       Aw = Al[apar ^ 1];
    const unsigned short* Bc = Bl[cb];
    unsigned short*       Bw = Bl[cb >= 1 ? cb - 1 : 2];   // (cb+2)%3

    short8 af[4], bf[4];

    // ---- P1: ks0 frag reads (8) + B(t+2) issue ----
#pragma unroll
    for (int fr = 0; fr < 4; ++fr) af[fr] = rdA(Ac, 0, fr);
#pragma unroll
    for (int fc = 0; fc < 4; ++fc) bf[fc] = rdB(Bc, 0, fc);
    if (mode & 2) issueB4(Bw, t + 2);
    __builtin_amdgcn_s_barrier();
    asm volatile("s_waitcnt lgkmcnt(0)" ::: "memory");
    __builtin_amdgcn_s_setprio(1);
#pragma unroll
    for (int fr = 0; fr < 4; ++fr)
#pragma unroll
      for (int fc = 0; fc < 4; ++fc)
        acc[fr][fc] = __builtin_amdgcn_mfma_f32_16x16x32_bf16(af[fr], bf[fc],
                                                              acc[fr][fc], 0, 0, 0);
    __builtin_amdgcn_s_setprio(0);
    __builtin_amdgcn_s_barrier();

    // ---- P2: ks1 frag reads (8) + A(t+1) stage; publish waits; MFMA ----
#pragma unroll
    for (int fr = 0; fr < 4; ++fr) af[fr] = rdA(Ac, 1, fr);
#pragma unroll
    for (int fc = 0; fc < 4; ++fc) bf[fc] = rdB(Bc, 1, fc);
    if (mode & 1) stageA(Aw, xs);
    asm volatile("s_waitcnt lgkmcnt(0)" ::: "memory");   // own reads + A-writes drained
    if (mode & 2) {
      asm volatile("s_waitcnt vmcnt(4)" ::: "memory");   // B(t+1) done; B(t+2) in flight
    } else {
      asm volatile("s_waitcnt vmcnt(0)" ::: "memory");   // tail tiles
    }
    __builtin_amdgcn_s_barrier();
    __builtin_amdgcn_s_setprio(1);
#pragma unroll
    for (int fr = 0; fr < 4; ++fr)
#pragma unroll
      for (int fc = 0; fc < 4; ++fc)
        acc[fr][fc] = __builtin_amdgcn_mfma_f32_16x16x32_bf16(af[fr], bf[fc],
                                                              acc[fr][fc], 0, 0, 0);
    __builtin_amdgcn_s_setprio(0);
    __builtin_amdgcn_s_barrier();   // closing barrier: t+1 buffers published
  };

  // ---- prologue: A(0)->Al[0]; B(0)->Bl[0], B(1)->Bl[1] (B(1) stays in flight) ----
  float4 xv = *(const float4*)xrow;             // x scalars for tiles 0..3
  stageA(Al[0], xv.x);
  issueB4(Bl[0], 0);
  issueB4(Bl[1], 1);
  asm volatile("s_waitcnt lgkmcnt(0)" ::: "memory");
  asm volatile("s_waitcnt vmcnt(4)" ::: "memory");   // B(0) resident; B(1) in flight
  __builtin_amdgcn_s_barrier();

  int cb = 0;                                    // t % 3
  for (int u = 0; u < 32; ++u) {
    float4 xvn = xv;
    if (u < 31) xvn = *(const float4*)(xrow + (u + 1) * 4);
    const int t0 = u * 4;
    tileF(t0 + 0, xv.y, 3, 0, cb); cb = (cb == 2) ? 0 : cb + 1;
    tileF(t0 + 1, xv.z, 3, 1, cb); cb = (cb == 2) ? 0 : cb + 1;
    tileF(t0 + 2, xv.w, 3, 0, cb); cb = (cb == 2) ? 0 : cb + 1;
    if (u < 31) {
      tileF(t0 + 3, xvn.x, 3, 1, cb);
    } else {          // t=127: stage bias tile A(128) = er (ih0) / 0 (ih1); no B(129)
      tileF(t0 + 3, bx, 1, 1, cb);
    }
    cb = (cb == 2) ? 0 : cb + 1;
    xv = xvn;
  }
  tileF(128, 0.f, 0, 0, cb);   // bias tile: compute only (cb == 128%3 == 2)

  // ---- epilogue: C layout col = lane&15, row = (lane>>4)*4 + j ----
#pragma unroll
  for (int fr = 0; fr < 4; ++fr) {
    const int r0 = m0 + wr * 64 + fr * 16 + (lane >> 4) * 4;
#pragma unroll
    for (int j = 0; j < 4; ++j) {
      const int rr = r0 + j;
      if (rr < Ntot) {
#pragma unroll
        for (int fc = 0; fc < 4; ++fc) {
          const int col = wc * 64 + fc * 16 + l15;
          out[(size_t)rr * O_DIM + col] = acc[fr][fc][j];
        }
      }
    }
  }
}

// ---- fallback (ws too small): simple 2-barrier kernel reading W/b directly ----
__global__ __launch_bounds__(256) void lkg_fb(
    const float* __restrict__ x, const float* __restrict__ e,
    const float* __restrict__ Wf, const float* __restrict__ bf32,
    float* __restrict__ out, int Ntot) {
  const int FBK = 64;
  const int FNT = (KW + 64) / FBK;
  __shared__ unsigned short Alds[128 * 64];
  __shared__ unsigned short Blds[256 * 64];

  const int tid = threadIdx.x, lane = tid & 63, wid = tid >> 6;
  const int wr = wid >> 1, wc = wid & 1, l15 = lane & 15, lk8 = (lane >> 4) * 8;
  const int m0 = (int)blockIdx.x * 128;
  const int srow = tid >> 1, skq = (tid & 1) * 32;
  const int gr = min(m0 + srow, Ntot - 1);

  f32x4 acc[4][8];
#pragma unroll
  for (int a = 0; a < 4; ++a)
#pragma unroll
    for (int c = 0; c < 8; ++c) acc[a][c] = (f32x4){0.f, 0.f, 0.f, 0.f};

  for (int t = 0; t < FNT; ++t) {
    const int k0 = t * FBK;
    float av[32];
    if (k0 < KW) {
      const int r = k0 >> 8, i0 = k0 & 255;
      const float ev = e[(size_t)gr * R_DIM + r];
#pragma unroll
      for (int p = 0; p < 8; ++p) {
        const float4 xvv = *(const float4*)&x[(size_t)gr * I_DIM + i0 + skq + p * 4];
        av[p * 4 + 0] = xvv.x * ev; av[p * 4 + 1] = xvv.y * ev;
        av[p * 4 + 2] = xvv.z * ev; av[p * 4 + 3] = xvv.w * ev;
      }
    } else {
#pragma unroll
      for (int s2 = 0; s2 < 32; ++s2) {
        const int kk = skq + s2;
        av[s2] = (kk < R_DIM) ? e[(size_t)gr * R_DIM + kk] : 0.f;
      }
    }
    const int bo = tid;
    if (k0 < KW) {
      const int r = k0 >> 8, i0 = k0 & 255;
#pragma unroll
      for (int h = 0; h < 4; ++h) {
        float bv[16];
#pragma unroll
        for (int p = 0; p < 4; ++p) {
          const float4 wv =
              *(const float4*)&Wf[((size_t)(r * O_DIM + bo)) * I_DIM + i0 + h * 16 + p * 4];
          bv[p * 4 + 0] = wv.x; bv[p * 4 + 1] = wv.y;
          bv[p * 4 + 2] = wv.z; bv[p * 4 + 3] = wv.w;
        }
#pragma unroll
        for (int g2 = 0; g2 < 2; ++g2) {
          ushort8 pw;
#pragma unroll
          for (int j = 0; j < 8; ++j) pw[j] = f2bf(bv[g2 * 8 + j]);
          *(ushort8*)&Blds[bo * FBK + h * 16 + g2 * 8] = pw;
        }
      }
    } else {
#pragma unroll
      for (int h = 0; h < 8; ++h) {
        ushort8 pw;
#pragma unroll
        for (int j = 0; j < 8; ++j) {
          const int kk = h * 8 + j;
          pw[j] = (kk < R_DIM) ? f2bf(bf32[kk * O_DIM + bo]) : (unsigned short)0;
        }
        *(ushort8*)&Blds[bo * FBK + h * 8] = pw;
      }
    }
#pragma unroll
    for (int h = 0; h < 4; ++h) {
      ushort8 pw;
#pragma unroll
      for (int j = 0; j < 8; ++j) pw[j] = f2bf(av[h * 8 + j]);
      *(ushort8*)&Alds[srow * FBK + skq + h * 8] = pw;
    }
    __syncthreads();
#pragma unroll
    for (int ks = 0; ks < 2; ++ks) {
      short8 af[4]; short8 bfr[8];
#pragma unroll
      for (int fr = 0; fr < 4; ++fr)
        af[fr] = *(const short8*)&Alds[(wr * 64 + fr * 16 + l15) * FBK + ks * 32 + lk8];
#pragma unroll
      for (int fc = 0; fc < 8; ++fc)
        bfr[fc] = *(const short8*)&Blds[(wc * 128 + fc * 16 + l15) * FBK + ks * 32 + lk8];
#pragma unroll
      for (int fr = 0; fr < 4; ++fr)
#pragma unroll
        for (int fc = 0; fc < 8; ++fc)
          acc[fr][fc] =
              __builtin_amdgcn_mfma_f32_16x16x32_bf16(af[fr], bfr[fc], acc[fr][fc], 0, 0, 0);
    }
    __syncthreads();
  }
#pragma unroll
  for (int fr = 0; fr < 4; ++fr) {
    const int r0 = m0 + wr * 64 + fr * 16 + (lane >> 4) * 4;
#pragma unroll
    for (int fc = 0; fc < 8; ++fc) {
      const int col = wc * 128 + fc * 16 + l15;
#pragma unroll
      for (int j = 0; j < 4; ++j) {
        const int rr = r0 + j;
        if (rr < Ntot) out[(size_t)rr * O_DIM + col] = acc[fr][fc][j];
      }
    }
  }
}

extern "C" void kernel_launch(void* const* d_in, const int* in_sizes, int n_in,
                              void* d_out, int out_size, void* d_ws, size_t ws_size,
                              hipStream_t stream) {
  const float* x = (const float*)d_in[0];
  const float* e = (const float*)d_in[1];
  const float* W = (const float*)d_in[2];
  const float* b = (const float*)d_in[3];
  float* out = (float*)d_out;
  const int Ntot = in_sizes[0] / I_DIM;

  const size_t wb_bytes = (size_t)O_DIM * KEXT * sizeof(unsigned short);
  if (ws_size >= wb_bytes) {
    unsigned short* Wb = (unsigned short*)d_ws;
    prep_w<<<(O_DIM * (KEXT / 4)) / 256, 256, 0, stream>>>(W, b, Wb);
    lkg2p<<<(Ntot + BM - 1) / BM, NTHR, 0, stream>>>(x, e, Wb, out, Ntot);
  } else {
    lkg_fb<<<(Ntot + 127) / 128, 256, 0, stream>>>(x, e, W, b, out, Ntot);
  }
}

// Round 9
// 519.614 us; speedup vs baseline: 4.4049x; 1.1687x over previous
//
#include <hip/hip_runtime.h>
#include <hip/hip_bf16.h>

// y[n,o] = sum_r e[n,r]*(W[r]@x[n])[o] + (e@b)[n,o]
// One bf16 GEMM, K = 8256: k = il*64 + ih*32 + r (i = 128*ih + il), bias tile appended.
// Tile t == il. A'[n,k] = e[n,r]*x[n,i] staged on the fly (R8 pattern: 4 thr/row,
// er[16]/thread, one x scalar per tile). B^T = Wb[o][k] bf16 in d_ws; LDS XOR-swizzled.
// R9 change: 2 BLOCKS/CU. BN=128 per block -> LDS 80KB (A 2x16 + B 3x16), acc[4][2]=32
// AGPR, waves_per_eu(4) pins 128-unified budget -> 16 waves/CU. Cross-block overlap
// hides the post-barrier lgkm drain (lockstep stall) and smooths the 3.05-round tail.

typedef __attribute__((ext_vector_type(4))) float f32x4;
typedef __attribute__((ext_vector_type(8))) short short8;
typedef __attribute__((ext_vector_type(8))) unsigned short ushort8;

#define R_DIM 32
#define I_DIM 256
#define O_DIM 256
#define KW    8192
#define KEXT  8256            // +64: [8192,8224)=b^T, rest 0
#define BM    128
#define BNB   128             // per-block N (2 N-blocks cover O=256)
#define BK    64
#define NT    (KEXT / BK)     // 129
#define NTHR  512

__device__ __forceinline__ unsigned short f2bf(float f) {
  unsigned u = __builtin_bit_cast(unsigned, f);
  u += 0x7FFFu + ((u >> 16) & 1u);  // RNE
  return (unsigned short)(u >> 16);
}

__device__ __forceinline__ unsigned pk2(float a, float b) {
  __hip_bfloat162 h = __float22bfloat162_rn(make_float2(a, b));  // v_cvt_pk_bf16_f32, RNE
  unsigned u;
  __builtin_memcpy(&u, &h, sizeof(u));
  return u;
}

__device__ __forceinline__ void gld_lds16(const void* g, void* l) {
  __builtin_amdgcn_global_load_lds(
      (const __attribute__((address_space(1))) unsigned int*)g,
      (__attribute__((address_space(3))) unsigned int*)l, 16, 0, 0);
}

// ---- prep: Wb[o][k] = bf16(W[r,o,i]), k = il*64+ih*32+r, i = 128*ih+il ----
__global__ void prep_w(const float* __restrict__ W, const float* __restrict__ b,
                       unsigned short* __restrict__ Wb) {
  const int id = blockIdx.x * 256 + threadIdx.x;   // 256 * 2064 threads exactly
  const int o  = id / (KEXT / 4);
  const int k4 = (id - o * (KEXT / 4)) * 4;
  float v[4];
  if (k4 < KW) {
    const int r  = k4 & 31;
    const int ih = (k4 >> 5) & 1;
    const int il = k4 >> 6;
    const int i  = 128 * ih + il;
#pragma unroll
    for (int j = 0; j < 4; ++j)
      v[j] = W[((size_t)((r + j) * O_DIM + o)) * I_DIM + i];
  } else {
    const int kk = k4 - KW;
#pragma unroll
    for (int j = 0; j < 4; ++j)
      v[j] = (kk + j < R_DIM) ? b[(kk + j) * O_DIM + o] : 0.f;
  }
  uint2 pk;
  pk.x = pk2(v[0], v[1]);
  pk.y = pk2(v[2], v[3]);
  *(uint2*)&Wb[(size_t)o * KEXT + k4] = pk;
}

// ---- main: 512 thr, 8 waves (2M x 4N), wave tile 64x32, 2 blocks/CU ----
__global__ __launch_bounds__(NTHR)
__attribute__((amdgpu_waves_per_eu(4)))
void lkg2b(
    const float* __restrict__ x, const float* __restrict__ e,
    const unsigned short* __restrict__ Wb, float* __restrict__ out, int Ntot) {
  __shared__ unsigned short Al[2][BM * BK];    // 2 x 16 KB
  __shared__ unsigned short Bl[3][BNB * BK];   // 3 x 16 KB  (80 KB total -> 2 blocks/CU)

  const int tid  = threadIdx.x;
  const int lane = tid & 63;
  const int w    = tid >> 6;     // 0..7
  const int wr   = w >> 2;       // 0..1  (M)
  const int wc   = w & 3;        // 0..3  (N)
  const int l15  = lane & 15;
  const int sx   = (l15 & 7) << 4;
  const int kb0  = (lane >> 4) << 4;

  const int mi = (int)blockIdx.x >> 1;     // M-tile
  const int ni = (int)blockIdx.x & 1;      // N-half
  const int m0 = mi * BM;
  const unsigned short* WbN = Wb + (size_t)(ni * BNB) * KEXT;

  const int srow = tid >> 2;               // 0..127: A row this thread stages
  const int q    = tid & 3;                // col quarter: ih = q>>1, r-half = q&1
  const int ih   = q >> 1;
  const int gr   = min(m0 + srow, Ntot - 1);

  // B gld_lds source-side swizzle (rule #21: linear dest + inverse-swz source)
  const int bro = lane >> 3;              // row within 8-row group
  const int bch = (lane & 7) ^ bro;       // pre-swizzled chunk index

  // e r-half in regs: er[j] = e[gr, (q&1)*16 + j]
  float er[16];
#pragma unroll
  for (int p = 0; p < 4; ++p) {
    const float4 ev = *(const float4*)&e[(size_t)gr * R_DIM + (q & 1) * 16 + p * 4];
    er[p * 4 + 0] = ev.x; er[p * 4 + 1] = ev.y;
    er[p * 4 + 2] = ev.z; er[p * 4 + 3] = ev.w;
  }
  const float* xrow = x + (size_t)gr * I_DIM + ih * 128;  // x scalar stream (il = t)
  const float biasx = (ih == 0) ? 1.f : 0.f;              // bias-tile scale

  f32x4 acc[4][2];
#pragma unroll
  for (int a = 0; a < 4; ++a)
#pragma unroll
    for (int c = 0; c < 2; ++c) acc[a][c] = (f32x4){0.f, 0.f, 0.f, 0.f};

  auto issueB2 = [&](unsigned short* Bd, int t2) {
    const size_t k0 = (size_t)t2 * BK;
#pragma unroll
    for (int g = 0; g < 2; ++g)
      gld_lds16(WbN + (size_t)(w * 16 + g * 8 + bro) * KEXT + k0 + bch * 8,
                Bd + (w * 16 + g * 8) * BK);
  };
  auto stageA = [&](unsigned short* Ad, float xs) {
    char* rowp = (char*)(Ad + srow * BK);
    const int sw = (srow & 7) << 4;
    const int qb = q * 32;
    uint4 wv;
    wv.x = pk2(xs * er[0], xs * er[1]);
    wv.y = pk2(xs * er[2], xs * er[3]);
    wv.z = pk2(xs * er[4], xs * er[5]);
    wv.w = pk2(xs * er[6], xs * er[7]);
    *(uint4*)(rowp + ((qb + 0) ^ sw)) = wv;
    uint4 wv2;
    wv2.x = pk2(xs * er[8],  xs * er[9]);
    wv2.y = pk2(xs * er[10], xs * er[11]);
    wv2.z = pk2(xs * er[12], xs * er[13]);
    wv2.w = pk2(xs * er[14], xs * er[15]);
    *(uint4*)(rowp + ((qb + 16) ^ sw)) = wv2;
  };
  auto rdA = [&](const unsigned short* Ab, int ks, int fr) -> short8 {
    const int row = wr * 64 + fr * 16 + l15;
    return *(const short8*)((const char*)Ab + row * 128 + ((ks * 64 + kb0) ^ sx));
  };
  auto rdB = [&](const unsigned short* Bb, int ks, int fc) -> short8 {
    const int row = wc * 32 + fc * 16 + l15;
    return *(const short8*)((const char*)Bb + row * 128 + ((ks * 64 + kb0) ^ sx));
  };

  // mode bits: 1 = stage A(t+1) with scale xs, 2 = issue B(t+2)
  auto tileF = [&](int t, float xs, int mode, int apar, int cb) {
    const unsigned short* Ac = Al[apar];
    unsigned short*       Aw = Al[apar ^ 1];
    const unsigned short* Bc = Bl[cb];
    unsigned short*       Bw = Bl[cb >= 1 ? cb - 1 : 2];   // (cb+2)%3

    short8 af[4], bf[2];

    // ---- P1: ks0 frag reads (6) + B(t+2) issue ----
#pragma unroll
    for (int fr = 0; fr < 4; ++fr) af[fr] = rdA(Ac, 0, fr);
#pragma unroll
    for (int fc = 0; fc < 2; ++fc) bf[fc] = rdB(Bc, 0, fc);
    if (mode & 2) issueB2(Bw, t + 2);
    __builtin_amdgcn_s_barrier();
    asm volatile("s_waitcnt lgkmcnt(0)" ::: "memory");
    __builtin_amdgcn_s_setprio(1);
#pragma unroll
    for (int fr = 0; fr < 4; ++fr)
#pragma unroll
      for (int fc = 0; fc < 2; ++fc)
        acc[fr][fc] = __builtin_amdgcn_mfma_f32_16x16x32_bf16(af[fr], bf[fc],
                                                              acc[fr][fc], 0, 0, 0);
    __builtin_amdgcn_s_setprio(0);
    __builtin_amdgcn_s_barrier();

    // ---- P2: ks1 frag reads (6) + A(t+1) stage; publish waits; MFMA ----
#pragma unroll
    for (int fr = 0; fr < 4; ++fr) af[fr] = rdA(Ac, 1, fr);
#pragma unroll
    for (int fc = 0; fc < 2; ++fc) bf[fc] = rdB(Bc, 1, fc);
    if (mode & 1) stageA(Aw, xs);
    asm volatile("s_waitcnt lgkmcnt(0)" ::: "memory");   // own reads + A-writes drained
    if (mode & 2) {
      asm volatile("s_waitcnt vmcnt(2)" ::: "memory");   // B(t+1) done; B(t+2) in flight
    } else {
      asm volatile("s_waitcnt vmcnt(0)" ::: "memory");   // tail tiles
    }
    __builtin_amdgcn_s_barrier();
    __builtin_amdgcn_s_setprio(1);
#pragma unroll
    for (int fr = 0; fr < 4; ++fr)
#pragma unroll
      for (int fc = 0; fc < 2; ++fc)
        acc[fr][fc] = __builtin_amdgcn_mfma_f32_16x16x32_bf16(af[fr], bf[fc],
                                                              acc[fr][fc], 0, 0, 0);
    __builtin_amdgcn_s_setprio(0);
    __builtin_amdgcn_s_barrier();   // closing barrier: t+1 buffers published
  };

  // ---- prologue: A(0)->Al[0]; B(0)->Bl[0], B(1)->Bl[1] (B(1) stays in flight) ----
  float4 xv = *(const float4*)xrow;             // x scalars for tiles 0..3
  stageA(Al[0], xv.x);
  issueB2(Bl[0], 0);
  issueB2(Bl[1], 1);
  asm volatile("s_waitcnt lgkmcnt(0)" ::: "memory");
  asm volatile("s_waitcnt vmcnt(2)" ::: "memory");   // B(0) resident; B(1) in flight
  __builtin_amdgcn_s_barrier();

  int cb = 0;                                    // t % 3
  for (int u = 0; u < 32; ++u) {
    float4 xvn = xv;
    if (u < 31) xvn = *(const float4*)(xrow + (u + 1) * 4);
    const int t0 = u * 4;
    tileF(t0 + 0, xv.y, 3, 0, cb); cb = (cb == 2) ? 0 : cb + 1;
    tileF(t0 + 1, xv.z, 3, 1, cb); cb = (cb == 2) ? 0 : cb + 1;
    tileF(t0 + 2, xv.w, 3, 0, cb); cb = (cb == 2) ? 0 : cb + 1;
    if (u < 31) {
      tileF(t0 + 3, xvn.x, 3, 1, cb);
    } else {          // t=127: stage bias tile A(128) = er (ih0) / 0 (ih1); no B(129)
      tileF(t0 + 3, biasx, 1, 1, cb);
    }
    cb = (cb == 2) ? 0 : cb + 1;
    xv = xvn;
  }
  tileF(128, 0.f, 0, 0, cb);   // bias tile: compute only (cb == 128%3 == 2)

  // ---- epilogue: C layout col = lane&15, row = (lane>>4)*4 + j ----
#pragma unroll
  for (int fr = 0; fr < 4; ++fr) {
    const int r0 = m0 + wr * 64 + fr * 16 + (lane >> 4) * 4;
#pragma unroll
    for (int j = 0; j < 4; ++j) {
      const int rr = r0 + j;
      if (rr < Ntot) {
#pragma unroll
        for (int fc = 0; fc < 2; ++fc) {
          const int col = ni * BNB + wc * 32 + fc * 16 + l15;
          out[(size_t)rr * O_DIM + col] = acc[fr][fc][j];
        }
      }
    }
  }
}

// ---- fallback (ws too small): simple 2-barrier kernel reading W/b directly ----
__global__ __launch_bounds__(256) void lkg_fb(
    const float* __restrict__ x, const float* __restrict__ e,
    const float* __restrict__ Wf, const float* __restrict__ bf32,
    float* __restrict__ out, int Ntot) {
  const int FBK = 64;
  const int FNT = (KW + 64) / FBK;
  __shared__ unsigned short Alds[128 * 64];
  __shared__ unsigned short Blds[256 * 64];

  const int tid = threadIdx.x, lane = tid & 63, wid = tid >> 6;
  const int wr = wid >> 1, wc = wid & 1, l15 = lane & 15, lk8 = (lane >> 4) * 8;
  const int m0 = (int)blockIdx.x * 128;
  const int srow = tid >> 1, skq = (tid & 1) * 32;
  const int gr = min(m0 + srow, Ntot - 1);

  f32x4 acc[4][8];
#pragma unroll
  for (int a = 0; a < 4; ++a)
#pragma unroll
    for (int c = 0; c < 8; ++c) acc[a][c] = (f32x4){0.f, 0.f, 0.f, 0.f};

  for (int t = 0; t < FNT; ++t) {
    const int k0 = t * FBK;
    float av[32];
    if (k0 < KW) {
      const int r = k0 >> 8, i0 = k0 & 255;
      const float ev = e[(size_t)gr * R_DIM + r];
#pragma unroll
      for (int p = 0; p < 8; ++p) {
        const float4 xvv = *(const float4*)&x[(size_t)gr * I_DIM + i0 + skq + p * 4];
        av[p * 4 + 0] = xvv.x * ev; av[p * 4 + 1] = xvv.y * ev;
        av[p * 4 + 2] = xvv.z * ev; av[p * 4 + 3] = xvv.w * ev;
      }
    } else {
#pragma unroll
      for (int s2 = 0; s2 < 32; ++s2) {
        const int kk = skq + s2;
        av[s2] = (kk < R_DIM) ? e[(size_t)gr * R_DIM + kk] : 0.f;
      }
    }
    const int bo = tid;
    if (k0 < KW) {
      const int r = k0 >> 8, i0 = k0 & 255;
#pragma unroll
      for (int h = 0; h < 4; ++h) {
        float bv[16];
#pragma unroll
        for (int p = 0; p < 4; ++p) {
          const float4 wv =
              *(const float4*)&Wf[((size_t)(r * O_DIM + bo)) * I_DIM + i0 + h * 16 + p * 4];
          bv[p * 4 + 0] = wv.x; bv[p * 4 + 1] = wv.y;
          bv[p * 4 + 2] = wv.z; bv[p * 4 + 3] = wv.w;
        }
#pragma unroll
        for (int g2 = 0; g2 < 2; ++g2) {
          ushort8 pw;
#pragma unroll
          for (int j = 0; j < 8; ++j) pw[j] = f2bf(bv[g2 * 8 + j]);
          *(ushort8*)&Blds[bo * FBK + h * 16 + g2 * 8] = pw;
        }
      }
    } else {
#pragma unroll
      for (int h = 0; h < 8; ++h) {
        ushort8 pw;
#pragma unroll
        for (int j = 0; j < 8; ++j) {
          const int kk = h * 8 + j;
          pw[j] = (kk < R_DIM) ? f2bf(bf32[kk * O_DIM + bo]) : (unsigned short)0;
        }
        *(ushort8*)&Blds[bo * FBK + h * 8] = pw;
      }
    }
#pragma unroll
    for (int h = 0; h < 4; ++h) {
      ushort8 pw;
#pragma unroll
      for (int j = 0; j < 8; ++j) pw[j] = f2bf(av[h * 8 + j]);
      *(ushort8*)&Alds[srow * FBK + skq + h * 8] = pw;
    }
    __syncthreads();
#pragma unroll
    for (int ks = 0; ks < 2; ++ks) {
      short8 af[4]; short8 bfr[8];
#pragma unroll
      for (int fr = 0; fr < 4; ++fr)
        af[fr] = *(const short8*)&Alds[(wr * 64 + fr * 16 + l15) * FBK + ks * 32 + lk8];
#pragma unroll
      for (int fc = 0; fc < 8; ++fc)
        bfr[fc] = *(const short8*)&Blds[(wc * 128 + fc * 16 + l15) * FBK + ks * 32 + lk8];
#pragma unroll
      for (int fr = 0; fr < 4; ++fr)
#pragma unroll
        for (int fc = 0; fc < 8; ++fc)
          acc[fr][fc] =
              __builtin_amdgcn_mfma_f32_16x16x32_bf16(af[fr], bfr[fc], acc[fr][fc], 0, 0, 0);
    }
    __syncthreads();
  }
#pragma unroll
  for (int fr = 0; fr < 4; ++fr) {
    const int r0 = m0 + wr * 64 + fr * 16 + (lane >> 4) * 4;
#pragma unroll
    for (int fc = 0; fc < 8; ++fc) {
      const int col = wc * 128 + fc * 16 + l15;
#pragma unroll
      for (int j = 0; j < 4; ++j) {
        const int rr = r0 + j;
        if (rr < Ntot) out[(size_t)rr * O_DIM + col] = acc[fr][fc][j];
      }
    }
  }
}

extern "C" void kernel_launch(void* const* d_in, const int* in_sizes, int n_in,
                              void* d_out, int out_size, void* d_ws, size_t ws_size,
                              hipStream_t stream) {
  const float* x = (const float*)d_in[0];
  const float* e = (const float*)d_in[1];
  const float* W = (const float*)d_in[2];
  const float* b = (const float*)d_in[3];
  float* out = (float*)d_out;
  const int Ntot = in_sizes[0] / I_DIM;

  const size_t wb_bytes = (size_t)O_DIM * KEXT * sizeof(unsigned short);
  if (ws_size >= wb_bytes) {
    unsigned short* Wb = (unsigned short*)d_ws;
    prep_w<<<(O_DIM * (KEXT / 4)) / 256, 256, 0, stream>>>(W, b, Wb);
    const int nb = ((Ntot + BM - 1) / BM) * 2;
    lkg2b<<<nb, NTHR, 0, stream>>>(x, e, Wb, out, Ntot);
  } else {
    lkg_fb<<<(Ntot + 127) / 128, 256, 0, stream>>>(x, e, W, b, out, Ntot);
  }
}